// Round 6
// baseline (68.517 us; speedup 1.0000x reference)
//
#include <hip/hip_runtime.h>
#include <hip/hip_bf16.h>
#include <stdint.h>

#define N_ATOMS 131072
#define D_IN    128
#define D_HID   256
#define N_ELEM  4
// buckets padded to 64-slot multiples; tiles are 32 atoms (64 | pad => 32 | pad)
#define NPAD    (N_ATOMS + N_ELEM * 64)   // 131328 slots max
#define K4_BLOCKS (NPAD / 128)             // 1026 blocks, 4 waves x 32 atoms each
#define HIST_BLOCKS 128                    // 128 x 1024 atoms

typedef __attribute__((ext_vector_type(8))) short bf16x8;
typedef __attribute__((ext_vector_type(4))) float f32x4;

// ws layout (bytes):
//   [0,       262144): W1t bf16 [4][256][128] (h-major, k contiguous)
//   [262144,  262160): counts[4]
//   [262176,  262200): startArr[5]
//   [262272,  266376): blockPartials[K4_BLOCKS] float
//   [270592,  272640): blockCounts[128][4] int
//   [278784,  280832): blockOff[128][4] int
//   [287232,  812544): sortedIdx[NPAD] int
#define WS_COUNTS 262144
#define WS_START  262176
#define WS_BPART  262272
#define WS_BCNT   270592
#define WS_BOFF   278784
#define WS_SIDX   287232

__device__ __forceinline__ unsigned short f2bf_rne(float f) {
    union { float f; unsigned u; } v; v.f = f;
    unsigned r = v.u + 0x7FFFu + ((v.u >> 16) & 1u);   // RNE
    return (unsigned short)(r >> 16);
}

// K1a: W1 [4][128][256] -> W1t bf16 [4][256][128] via LDS 64x64 tile transpose.
// 32 blocks: e(4) x ktile(2) x htile(4). Coalesced reads and writes.
__global__ void tnn_k1a_w1t(const float* __restrict__ W1, unsigned short* __restrict__ W1t) {
    __shared__ float tile[64][65];
    int b  = blockIdx.x;
    int e  = b >> 3;
    int k0 = ((b >> 2) & 1) * 64;
    int h0 = (b & 3) * 64;
    int t  = threadIdx.x;
    int cg = t & 15;          // 16B column group
    int rr = t >> 4;          // 0..15

    const float* src = W1 + ((size_t)e * D_IN + k0) * D_HID + h0;
    #pragma unroll
    for (int j = 0; j < 4; ++j) {
        int row = rr + j * 16;                       // k-local
        f32x4 v = *(const f32x4*)(src + (size_t)row * D_HID + cg * 4);
        tile[row][cg * 4 + 0] = v[0];
        tile[row][cg * 4 + 1] = v[1];
        tile[row][cg * 4 + 2] = v[2];
        tile[row][cg * 4 + 3] = v[3];
    }
    __syncthreads();
    unsigned short* dst = W1t + ((size_t)e * D_HID + h0) * D_IN + k0;
    #pragma unroll
    for (int j = 0; j < 4; ++j) {
        int hrow = rr + j * 16;                      // h-local
        ushort4 o;
        o.x = f2bf_rne(tile[cg * 4 + 0][hrow]);
        o.y = f2bf_rne(tile[cg * 4 + 1][hrow]);
        o.z = f2bf_rne(tile[cg * 4 + 2][hrow]);
        o.w = f2bf_rne(tile[cg * 4 + 3][hrow]);
        *(ushort4*)(dst + (size_t)hrow * D_IN + cg * 4) = o;
    }
}

// K1b: per-block histogram, register counters + LDS reduce-free atomics.
__global__ void tnn_k1b_hist(const int* __restrict__ eid, int* __restrict__ bcnt) {
    __shared__ int lc[N_ELEM];
    int t = threadIdx.x;
    if (t < N_ELEM) lc[t] = 0;
    __syncthreads();
    int base = blockIdx.x * 1024;
    #pragma unroll
    for (int r = 0; r < 4; ++r)
        atomicAdd(&lc[eid[base + r * 256 + t]], 1);
    __syncthreads();
    if (t < N_ELEM) bcnt[blockIdx.x * 4 + t] = lc[t];
}

// K2: one wave, shfl scan of 128 int4 block counts -> counts/starts/blockOff.
__global__ void tnn_k2_scan(const int* __restrict__ bcnt, int* __restrict__ counts,
                            int* __restrict__ startArr, int* __restrict__ boff) {
    int t = threadIdx.x;     // 0..63
    int4 c0 = ((const int4*)bcnt)[2 * t];
    int4 c1 = ((const int4*)bcnt)[2 * t + 1];
    int4 s  = {c0.x + c1.x, c0.y + c1.y, c0.z + c1.z, c0.w + c1.w};
    int4 incl = s;
    #pragma unroll
    for (int off = 1; off < 64; off <<= 1) {
        int ux = __shfl_up(incl.x, off);
        int uy = __shfl_up(incl.y, off);
        int uz = __shfl_up(incl.z, off);
        int uw = __shfl_up(incl.w, off);
        if (t >= off) { incl.x += ux; incl.y += uy; incl.z += uz; incl.w += uw; }
    }
    int4 tot = {__shfl(incl.x, 63), __shfl(incl.y, 63), __shfl(incl.z, 63), __shfl(incl.w, 63)};
    int st0 = 0;
    int st1 = st0 + ((tot.x + 63) & ~63);
    int st2 = st1 + ((tot.y + 63) & ~63);
    int st3 = st2 + ((tot.z + 63) & ~63);
    int st4 = st3 + ((tot.w + 63) & ~63);
    int4 run = {incl.x - s.x, incl.y - s.y, incl.z - s.z, incl.w - s.w};  // exclusive
    int4 o0 = {st0 + run.x, st1 + run.y, st2 + run.z, st3 + run.w};
    ((int4*)boff)[2 * t] = o0;
    run.x += c0.x; run.y += c0.y; run.z += c0.z; run.w += c0.w;
    int4 o1 = {st0 + run.x, st1 + run.y, st2 + run.z, st3 + run.w};
    ((int4*)boff)[2 * t + 1] = o1;
    if (t == 0) {
        ((int4*)counts)[0] = tot;
        startArr[0] = st0; startArr[1] = st1; startArr[2] = st2;
        startArr[3] = st3; startArr[4] = st4;
    }
}

// K3: scatter with per-block bases (LDS rank atomics only).
__global__ void tnn_k3_scatter(const int* __restrict__ eid, const int* __restrict__ boff,
                               int* __restrict__ sortedIdx) {
    __shared__ int lc[N_ELEM];
    int t = threadIdx.x;
    if (t < N_ELEM) lc[t] = 0;
    __syncthreads();
    int base = blockIdx.x * 1024;
    #pragma unroll
    for (int r = 0; r < 4; ++r) {
        int i = base + r * 256 + t;
        int e = eid[i];
        int rank = atomicAdd(&lc[e], 1);
        sortedIdx[boff[blockIdx.x * 4 + e] + rank] = i;
    }
}

// K4: wave = 32 sorted atoms x 256 hidden. A in registers (32 VGPR), B streamed
// from L1/L2 with one-ahead prefetch. No LDS staging, no hot-path barriers.
__global__ __launch_bounds__(256, 4) void tnn_k4_mlp(
        const float* __restrict__ X, const int* __restrict__ sortedIdx,
        const int* __restrict__ startArr, const int* __restrict__ counts,
        const unsigned short* __restrict__ W1t, const float* __restrict__ b1,
        const float* __restrict__ W2, float* __restrict__ bpart) {
    __shared__ float red[4];
    const float C2 = 2.8853900817779268f;   // 2*log2(e)

    int t = threadIdx.x;
    int wid  = t >> 6;
    int lane = t & 63;
    int l15  = lane & 15;
    int lk   = lane >> 4;
    int tb   = (blockIdx.x * 4 + wid) * 32;
    int total = startArr[N_ELEM];

    float partial = 0.f;
    if (tb < total) {
        int e = 0;
        while (tb >= startArr[e + 1]) ++e;           // wave-uniform
        int rend = startArr[e] + counts[e];
        bool full = (tb + 32 <= rend);
        int fb = sortedIdx[startArr[e]];             // always-valid fallback row

        // ---- A fragments: 32 atoms x 128 k, bf16 (trunc), in registers ----
        bf16x8 a[2][4];
        #pragma unroll
        for (int m = 0; m < 2; ++m) {
            int slot = tb + m * 16 + l15;
            int row = (slot < rend) ? sortedIdx[slot] : fb;
            const float* xr = X + (size_t)row * D_IN + lk * 8;
            #pragma unroll
            for (int ks = 0; ks < 4; ++ks) {
                f32x4 v0 = *(const f32x4*)(xr + ks * 32);
                f32x4 v1 = *(const f32x4*)(xr + ks * 32 + 4);
                bf16x8 tv;
                tv[0] = (short)(__float_as_uint(v0[0]) >> 16);
                tv[1] = (short)(__float_as_uint(v0[1]) >> 16);
                tv[2] = (short)(__float_as_uint(v0[2]) >> 16);
                tv[3] = (short)(__float_as_uint(v0[3]) >> 16);
                tv[4] = (short)(__float_as_uint(v1[0]) >> 16);
                tv[5] = (short)(__float_as_uint(v1[1]) >> 16);
                tv[6] = (short)(__float_as_uint(v1[2]) >> 16);
                tv[7] = (short)(__float_as_uint(v1[3]) >> 16);
                a[m][ks] = tv;
            }
        }

        float fnval = 8.f;
        if (!full) {
            int nv = 0;
            #pragma unroll
            for (int m = 0; m < 2; ++m)
                #pragma unroll
                for (int r = 0; r < 4; ++r)
                    nv += (tb + m * 16 + lk * 4 + r < rend) ? 1 : 0;
            fnval = (float)nv;
        }

        const unsigned short* wr = W1t + (size_t)e * D_HID * D_IN + (size_t)l15 * D_IN + lk * 8;
        const float* b1p = b1 + e * D_HID + l15;
        const float* w2p = W2 + e * D_HID + l15;

        bf16x8 cur[4], nxt[4];
        #pragma unroll
        for (int ks = 0; ks < 4; ++ks) cur[ks] = *(const bf16x8*)(wr + ks * 32);
        float b1v = b1p[0], w2v = w2p[0];

        #pragma unroll 2
        for (int nt = 0; nt < 16; ++nt) {
            int ntn = (nt < 15) ? nt + 1 : 15;       // dup prefetch at tail, harmless
            const unsigned short* wn = wr + (size_t)ntn * 16 * D_IN;
            #pragma unroll
            for (int ks = 0; ks < 4; ++ks) nxt[ks] = *(const bf16x8*)(wn + ks * 32);
            float b1n = b1p[ntn * 16];
            float w2n = w2p[ntn * 16];

            f32x4 acc0 = {0.f, 0.f, 0.f, 0.f};
            f32x4 acc1 = {0.f, 0.f, 0.f, 0.f};
            #pragma unroll
            for (int ks = 0; ks < 4; ++ks) {
                acc0 = __builtin_amdgcn_mfma_f32_16x16x32_bf16(a[0][ks], cur[ks], acc0, 0, 0, 0);
                acc1 = __builtin_amdgcn_mfma_f32_16x16x32_bf16(a[1][ks], cur[ks], acc1, 0, 0, 0);
            }

            // tanh(p) = 1 - 2/(exp2(C2*p)+1); sum w2*tanh = w2*(nval - 2*sum(rcp))
            float b1s = b1v * C2;
            float rsum = 0.f;
            #pragma unroll
            for (int r = 0; r < 4; ++r) {
                float e0 = __builtin_amdgcn_exp2f(fmaf(C2, acc0[r], b1s));
                float e1 = __builtin_amdgcn_exp2f(fmaf(C2, acc1[r], b1s));
                float rc0 = __builtin_amdgcn_rcpf(e0 + 1.f);
                float rc1 = __builtin_amdgcn_rcpf(e1 + 1.f);
                if (!full) {
                    rc0 = (tb + lk * 4 + r      < rend) ? rc0 : 0.f;
                    rc1 = (tb + 16 + lk * 4 + r < rend) ? rc1 : 0.f;
                }
                rsum += rc0 + rc1;
            }
            partial = fmaf(w2v, fmaf(-2.f, rsum, fnval), partial);

            #pragma unroll
            for (int ks = 0; ks < 4; ++ks) cur[ks] = nxt[ks];
            b1v = b1n; w2v = w2n;
        }
    }

    #pragma unroll
    for (int off = 32; off; off >>= 1)
        partial += __shfl_down(partial, off);
    if (lane == 0) red[wid] = partial;
    __syncthreads();
    if (t == 0)
        bpart[blockIdx.x] = red[0] + red[1] + red[2] + red[3];   // plain store
}

// K5: single block reduces block partials + analytic bias term.
__global__ void tnn_k5_reduce(const float* __restrict__ bpart, const int* __restrict__ counts,
                              const float* __restrict__ b2, float* __restrict__ out) {
    __shared__ float r[4];
    int t = threadIdx.x;
    float s = 0.f;
    for (int i = t; i < K4_BLOCKS; i += 256) s += bpart[i];
    #pragma unroll
    for (int off = 32; off; off >>= 1)
        s += __shfl_down(s, off);
    if ((t & 63) == 0) r[t >> 6] = s;
    __syncthreads();
    if (t == 0) {
        float acc = r[0] + r[1] + r[2] + r[3];
        #pragma unroll
        for (int e = 0; e < N_ELEM; ++e)
            acc += (float)counts[e] * b2[e];   // b2 is [E,1]
        out[0] = acc;
    }
}

extern "C" void kernel_launch(void* const* d_in, const int* in_sizes, int n_in,
                              void* d_out, int out_size, void* d_ws, size_t ws_size,
                              hipStream_t stream) {
    const float* X   = (const float*)d_in[0];
    const int*   eid = (const int*)  d_in[1];
    const float* W1  = (const float*)d_in[2];
    const float* b1  = (const float*)d_in[3];
    const float* W2  = (const float*)d_in[4];
    const float* b2  = (const float*)d_in[5];
    float* out = (float*)d_out;

    char* ws = (char*)d_ws;
    unsigned short* W1t = (unsigned short*)ws;
    int*   counts    = (int*)  (ws + WS_COUNTS);
    int*   startArr  = (int*)  (ws + WS_START);
    float* bpart     = (float*)(ws + WS_BPART);
    int*   bcnt      = (int*)  (ws + WS_BCNT);
    int*   boff      = (int*)  (ws + WS_BOFF);
    int*   sortedIdx = (int*)  (ws + WS_SIDX);

    hipLaunchKernelGGL(tnn_k1a_w1t,    dim3(32),          dim3(256), 0, stream, W1, W1t);
    hipLaunchKernelGGL(tnn_k1b_hist,   dim3(HIST_BLOCKS), dim3(256), 0, stream, eid, bcnt);
    hipLaunchKernelGGL(tnn_k2_scan,    dim3(1),           dim3(64),  0, stream, bcnt, counts, startArr, boff);
    hipLaunchKernelGGL(tnn_k3_scatter, dim3(HIST_BLOCKS), dim3(256), 0, stream, eid, boff, sortedIdx);
    hipLaunchKernelGGL(tnn_k4_mlp,     dim3(K4_BLOCKS),   dim3(256), 0, stream,
                       X, sortedIdx, startArr, counts, W1t, b1, W2, bpart);
    hipLaunchKernelGGL(tnn_k5_reduce,  dim3(1),           dim3(256), 0, stream, bpart, counts, b2, out);
}

// Round 7
// 54.941 us; speedup vs baseline: 1.2471x; 1.2471x over previous
//
#include <hip/hip_runtime.h>
#include <hip/hip_bf16.h>
#include <stdint.h>

#define N_ATOMS 131072
#define D_IN    128
#define D_HID   256
#define N_ELEM  4
#define NPAD    (N_ATOMS + N_ELEM * 64)   // 131328 slots max
#define K4_BLOCKS 512                      // persistent, 2/CU, expert = b&3
#define HIST_BLOCKS 128                    // 128 x 1024 atoms

typedef __attribute__((ext_vector_type(8))) short bf16x8;
typedef __attribute__((ext_vector_type(4))) float f32x4;

// ws layout (bytes):
//   [0,       262144): W1t bf16 [4][256][128] (h-major, k contiguous)
//   [262144,  262160): counts[4]
//   [262176,  262200): startArr[5]
//   [262272,  264320): blockPartials[512] float
//   [270592,  272640): blockCounts[128][4] int
//   [278784,  280832): blockOff[128][4] int
//   [287232,  812544): sortedIdx[NPAD] int
#define WS_COUNTS 262144
#define WS_START  262176
#define WS_BPART  262272
#define WS_BCNT   270592
#define WS_BOFF   278784
#define WS_SIDX   287232

__device__ __forceinline__ unsigned short f2bf_rne(float f) {
    union { float f; unsigned u; } v; v.f = f;
    unsigned r = v.u + 0x7FFFu + ((v.u >> 16) & 1u);   // RNE
    return (unsigned short)(r >> 16);
}

// K1 (fused): blocks 0..31 transpose W1 -> W1t bf16; blocks 32..159 histogram.
__global__ void tnn_k1_fused(const int* __restrict__ eid, int* __restrict__ bcnt,
                             const float* __restrict__ W1, unsigned short* __restrict__ W1t) {
    __shared__ float tile[64][65];
    __shared__ int lc[N_ELEM];
    int t = threadIdx.x;
    if (blockIdx.x < 32) {
        // ---- W1 [4][128][256] -> W1t [4][256][128] via 64x64 LDS transpose ----
        int b  = blockIdx.x;
        int e  = b >> 3;
        int k0 = ((b >> 2) & 1) * 64;
        int h0 = (b & 3) * 64;
        int cg = t & 15;
        int rr = t >> 4;
        const float* src = W1 + ((size_t)e * D_IN + k0) * D_HID + h0;
        #pragma unroll
        for (int j = 0; j < 4; ++j) {
            int row = rr + j * 16;
            f32x4 v = *(const f32x4*)(src + (size_t)row * D_HID + cg * 4);
            tile[row][cg * 4 + 0] = v[0];
            tile[row][cg * 4 + 1] = v[1];
            tile[row][cg * 4 + 2] = v[2];
            tile[row][cg * 4 + 3] = v[3];
        }
        __syncthreads();
        unsigned short* dst = W1t + ((size_t)e * D_HID + h0) * D_IN + k0;
        #pragma unroll
        for (int j = 0; j < 4; ++j) {
            int hrow = rr + j * 16;
            ushort4 o;
            o.x = f2bf_rne(tile[cg * 4 + 0][hrow]);
            o.y = f2bf_rne(tile[cg * 4 + 1][hrow]);
            o.z = f2bf_rne(tile[cg * 4 + 2][hrow]);
            o.w = f2bf_rne(tile[cg * 4 + 3][hrow]);
            *(ushort4*)(dst + (size_t)hrow * D_IN + cg * 4) = o;
        }
    } else {
        // ---- per-block histogram over 1024 atoms ----
        int hb = blockIdx.x - 32;
        if (t < N_ELEM) lc[t] = 0;
        __syncthreads();
        int base = hb * 1024;
        #pragma unroll
        for (int r = 0; r < 4; ++r)
            atomicAdd(&lc[eid[base + r * 256 + t]], 1);
        __syncthreads();
        if (t < N_ELEM) bcnt[hb * 4 + t] = lc[t];
    }
}

// K2: one wave, shfl scan of 128 int4 block counts -> counts/starts/blockOff.
__global__ void tnn_k2_scan(const int* __restrict__ bcnt, int* __restrict__ counts,
                            int* __restrict__ startArr, int* __restrict__ boff) {
    int t = threadIdx.x;     // 0..63
    int4 c0 = ((const int4*)bcnt)[2 * t];
    int4 c1 = ((const int4*)bcnt)[2 * t + 1];
    int4 s  = {c0.x + c1.x, c0.y + c1.y, c0.z + c1.z, c0.w + c1.w};
    int4 incl = s;
    #pragma unroll
    for (int off = 1; off < 64; off <<= 1) {
        int ux = __shfl_up(incl.x, off);
        int uy = __shfl_up(incl.y, off);
        int uz = __shfl_up(incl.z, off);
        int uw = __shfl_up(incl.w, off);
        if (t >= off) { incl.x += ux; incl.y += uy; incl.z += uz; incl.w += uw; }
    }
    int4 tot = {__shfl(incl.x, 63), __shfl(incl.y, 63), __shfl(incl.z, 63), __shfl(incl.w, 63)};
    int st0 = 0;
    int st1 = st0 + ((tot.x + 63) & ~63);
    int st2 = st1 + ((tot.y + 63) & ~63);
    int st3 = st2 + ((tot.z + 63) & ~63);
    int st4 = st3 + ((tot.w + 63) & ~63);
    int4 run = {incl.x - s.x, incl.y - s.y, incl.z - s.z, incl.w - s.w};  // exclusive
    int4 o0 = {st0 + run.x, st1 + run.y, st2 + run.z, st3 + run.w};
    ((int4*)boff)[2 * t] = o0;
    run.x += c0.x; run.y += c0.y; run.z += c0.z; run.w += c0.w;
    int4 o1 = {st0 + run.x, st1 + run.y, st2 + run.z, st3 + run.w};
    ((int4*)boff)[2 * t + 1] = o1;
    if (t == 0) {
        ((int4*)counts)[0] = tot;
        startArr[0] = st0; startArr[1] = st1; startArr[2] = st2;
        startArr[3] = st3; startArr[4] = st4;
    }
}

// K3: scatter with per-block bases (LDS rank atomics only).
__global__ void tnn_k3_scatter(const int* __restrict__ eid, const int* __restrict__ boff,
                               int* __restrict__ sortedIdx) {
    __shared__ int lc[N_ELEM];
    int t = threadIdx.x;
    if (t < N_ELEM) lc[t] = 0;
    __syncthreads();
    int base = blockIdx.x * 1024;
    #pragma unroll
    for (int r = 0; r < 4; ++r) {
        int i = base + r * 256 + t;
        int e = eid[i];
        int rank = atomicAdd(&lc[e], 1);
        sortedIdx[boff[blockIdx.x * 4 + e] + rank] = i;
    }
}

// K4: persistent blocks; expert = blockIdx&3. Each wave holds its 64-h-row
// B-quarter of W1t ENTIRELY in registers (64 VGPR), loaded once, then loops
// over 64-atom tiles. No loads on the MFMA dependency path.
__global__ __launch_bounds__(256, 2) void tnn_k4_mlp(
        const float* __restrict__ X, const int* __restrict__ sortedIdx,
        const int* __restrict__ startArr, const int* __restrict__ counts,
        const unsigned short* __restrict__ W1t, const float* __restrict__ b1,
        const float* __restrict__ W2, float* __restrict__ bpart) {
    __shared__ float red[4];
    const float C2 = 2.8853900817779268f;   // 2*log2(e)

    int t = threadIdx.x;
    int wid  = t >> 6;
    int lane = t & 63;
    int l15  = lane & 15;
    int lk   = lane >> 4;

    int e      = blockIdx.x & 3;
    int q      = blockIdx.x >> 2;            // 0..127, tile stride 128
    int bstart = startArr[e];
    int cnt    = counts[e];
    int rend   = bstart + cnt;
    int Te     = (startArr[e + 1] - bstart) >> 6;   // padded tile count
    int fb     = (cnt > 0) ? sortedIdx[bstart] : 0; // always-valid fallback row

    // ---- B: 64 h-rows x 128 k, bf16, register-resident for the whole kernel ----
    bf16x8 b[4][4];
    float b1v[4], w2v[4];
    {
        const unsigned short* wbase = W1t + ((size_t)e * D_HID + wid * 64 + l15) * D_IN + lk * 8;
        #pragma unroll
        for (int nt = 0; nt < 4; ++nt) {
            #pragma unroll
            for (int ks = 0; ks < 4; ++ks)
                b[nt][ks] = *(const bf16x8*)(wbase + (size_t)nt * 16 * D_IN + ks * 32);
            b1v[nt] = b1[e * D_HID + wid * 64 + nt * 16 + l15];
            w2v[nt] = W2[e * D_HID + wid * 64 + nt * 16 + l15];
        }
    }

    float partial = 0.f;
    for (int tt = q; tt < Te; tt += 128) {
        int tb = bstart + tt * 64;
        bool full = (tb + 64 <= rend);

        // ---- A: gather 64 atoms x 128 k -> bf16 regs (trunc) ----
        bf16x8 a[4][4];
        #pragma unroll
        for (int m = 0; m < 4; ++m) {
            int slot = tb + m * 16 + l15;
            int row = (slot < rend) ? sortedIdx[slot] : fb;
            const float* xr = X + (size_t)row * D_IN + lk * 8;
            #pragma unroll
            for (int ks = 0; ks < 4; ++ks) {
                f32x4 v0 = *(const f32x4*)(xr + ks * 32);
                f32x4 v1 = *(const f32x4*)(xr + ks * 32 + 4);
                bf16x8 tv;
                tv[0] = (short)(__float_as_uint(v0[0]) >> 16);
                tv[1] = (short)(__float_as_uint(v0[1]) >> 16);
                tv[2] = (short)(__float_as_uint(v0[2]) >> 16);
                tv[3] = (short)(__float_as_uint(v0[3]) >> 16);
                tv[4] = (short)(__float_as_uint(v1[0]) >> 16);
                tv[5] = (short)(__float_as_uint(v1[1]) >> 16);
                tv[6] = (short)(__float_as_uint(v1[2]) >> 16);
                tv[7] = (short)(__float_as_uint(v1[3]) >> 16);
                a[m][ks] = tv;
            }
        }

        float fnval = 16.f;
        if (!full) {
            int nv = 0;
            #pragma unroll
            for (int m = 0; m < 4; ++m)
                #pragma unroll
                for (int r = 0; r < 4; ++r)
                    nv += (tb + m * 16 + lk * 4 + r < rend) ? 1 : 0;
            fnval = (float)nv;
        }

        #pragma unroll
        for (int nt = 0; nt < 4; ++nt) {
            f32x4 acc[4];
            #pragma unroll
            for (int m = 0; m < 4; ++m) {
                acc[m] = f32x4{0.f, 0.f, 0.f, 0.f};
                #pragma unroll
                for (int ks = 0; ks < 4; ++ks)
                    acc[m] = __builtin_amdgcn_mfma_f32_16x16x32_bf16(a[m][ks], b[nt][ks], acc[m], 0, 0, 0);
            }

            // tanh(p) = 1 - 2/(exp2(C2*p)+1); sum w2*tanh = w2*(nval - 2*sum(rcp))
            float b1s = b1v[nt] * C2;
            float rsum = 0.f;
            #pragma unroll
            for (int m = 0; m < 4; ++m) {
                #pragma unroll
                for (int r = 0; r < 4; ++r) {
                    float exv = __builtin_amdgcn_exp2f(fmaf(C2, acc[m][r], b1s));
                    float rc  = __builtin_amdgcn_rcpf(exv + 1.f);
                    if (!full)
                        rc = (tb + m * 16 + lk * 4 + r < rend) ? rc : 0.f;
                    rsum += rc;
                }
            }
            partial = fmaf(w2v[nt], fmaf(-2.f, rsum, fnval), partial);
        }
    }

    #pragma unroll
    for (int off = 32; off; off >>= 1)
        partial += __shfl_down(partial, off);
    if (lane == 0) red[wid] = partial;
    __syncthreads();
    if (t == 0)
        bpart[blockIdx.x] = red[0] + red[1] + red[2] + red[3];   // plain store
}

// K5: single block reduces 512 block partials + analytic bias term.
__global__ void tnn_k5_reduce(const float* __restrict__ bpart, const int* __restrict__ counts,
                              const float* __restrict__ b2, float* __restrict__ out) {
    __shared__ float r[4];
    int t = threadIdx.x;
    float s = bpart[t] + bpart[t + 256];
    #pragma unroll
    for (int off = 32; off; off >>= 1)
        s += __shfl_down(s, off);
    if ((t & 63) == 0) r[t >> 6] = s;
    __syncthreads();
    if (t == 0) {
        float acc = r[0] + r[1] + r[2] + r[3];
        #pragma unroll
        for (int e = 0; e < N_ELEM; ++e)
            acc += (float)counts[e] * b2[e];   // b2 is [E,1]
        out[0] = acc;
    }
}

extern "C" void kernel_launch(void* const* d_in, const int* in_sizes, int n_in,
                              void* d_out, int out_size, void* d_ws, size_t ws_size,
                              hipStream_t stream) {
    const float* X   = (const float*)d_in[0];
    const int*   eid = (const int*)  d_in[1];
    const float* W1  = (const float*)d_in[2];
    const float* b1  = (const float*)d_in[3];
    const float* W2  = (const float*)d_in[4];
    const float* b2  = (const float*)d_in[5];
    float* out = (float*)d_out;

    char* ws = (char*)d_ws;
    unsigned short* W1t = (unsigned short*)ws;
    int*   counts    = (int*)  (ws + WS_COUNTS);
    int*   startArr  = (int*)  (ws + WS_START);
    float* bpart     = (float*)(ws + WS_BPART);
    int*   bcnt      = (int*)  (ws + WS_BCNT);
    int*   boff      = (int*)  (ws + WS_BOFF);
    int*   sortedIdx = (int*)  (ws + WS_SIDX);

    hipLaunchKernelGGL(tnn_k1_fused,   dim3(32 + HIST_BLOCKS), dim3(256), 0, stream, eid, bcnt, W1, W1t);
    hipLaunchKernelGGL(tnn_k2_scan,    dim3(1),                dim3(64),  0, stream, bcnt, counts, startArr, boff);
    hipLaunchKernelGGL(tnn_k3_scatter, dim3(HIST_BLOCKS),      dim3(256), 0, stream, eid, boff, sortedIdx);
    hipLaunchKernelGGL(tnn_k4_mlp,     dim3(K4_BLOCKS),        dim3(256), 0, stream,
                       X, sortedIdx, startArr, counts, W1t, b1, W2, bpart);
    hipLaunchKernelGGL(tnn_k5_reduce,  dim3(1),                dim3(256), 0, stream, bpart, counts, b2, out);
}